// Round 2
// baseline (303.181 us; speedup 1.0000x reference)
//
#include <hip/hip_runtime.h>
#include <hip/hip_bf16.h>
#include <stdint.h>

// Problem constants (B,C,H,W)=(16,256,64,64), HEADS=8, BS=8, HALO=3
// Inputs f32; MFMA math bf16, f32 accumulate; output f32.
#define HEADS 8
#define WIN 14
#define NPOS 196          // WIN*WIN
#define NPAD 224          // padded key count = 7*32
#define NB 16
#define NC 256
#define NH 64
#define NW 64
#define NP 4096           // NH*NW
#define NKV 512           // kv channels (fallback layout)
#define NOC 768           // q(256) + kv(512) channels

typedef __bf16 bf16_t;
typedef bf16_t bf16x8 __attribute__((ext_vector_type(8)));
typedef float f32x4 __attribute__((ext_vector_type(4)));

union Frag {
  uint4 u4;
  bf16x8 b8;
  ushort us[8];
};

__device__ __forceinline__ ushort f2bf(float f) {
  bf16_t h = (bf16_t)f;
  return __builtin_bit_cast(ushort, h);
}
__device__ __forceinline__ bf16x8 load_bf8(const float* __restrict__ p) {
  float4 a = *reinterpret_cast<const float4*>(p);
  float4 b = *reinterpret_cast<const float4*>(p + 4);
  bf16x8 r;
  r[0] = (bf16_t)a.x; r[1] = (bf16_t)a.y; r[2] = (bf16_t)a.z; r[3] = (bf16_t)a.w;
  r[4] = (bf16_t)b.x; r[5] = (bf16_t)b.y; r[6] = (bf16_t)b.z; r[7] = (bf16_t)b.w;
  return r;
}

// direct global->LDS DMA, 16B per lane
__device__ __forceinline__ void gload_lds16(const ushort* g, ushort* l) {
#if __has_builtin(__builtin_amdgcn_global_load_lds)
  __builtin_amdgcn_global_load_lds(
      (const __attribute__((address_space(1))) unsigned int*)(const void*)g,
      (__attribute__((address_space(3))) unsigned int*)(void*)l, 16, 0, 0);
#else
  *reinterpret_cast<uint4*>(l) = *reinterpret_cast<const uint4*>(g);
#endif
}

// bf16 weights, converted once per launch (same data every call)
__device__ ushort g_wb[NOC * NC];
// transposed + key-padded pos bias: [h][key(224)][q(64)], pad keys = -3e4
__device__ float g_pbt[HEADS * NPAD * 64];

// ===========================================================================
// k_wcast: [Wq;Wkv] f32 -> g_wb bf16. 96 wg x 256 thr x 8 elem.
// ===========================================================================
__global__ __launch_bounds__(256) void k_wcast(const float* __restrict__ wq,
                                               const float* __restrict__ wkv) {
  int idx = (blockIdx.x * 256 + threadIdx.x) * 8;
  int oc = idx >> 8, c = idx & 255;
  const float* src = (oc < 256) ? (wq + (size_t)oc * NC + c)
                                : (wkv + (size_t)(oc - 256) * NC + c);
  Frag v;
  v.b8 = load_bf8(src);
  *reinterpret_cast<uint4*>(g_wb + idx) = v.u4;
}

// ===========================================================================
// k_pbt: pos_bias [h][q][key(196)] f32 -> g_pbt [h][key(224)][q] f32.
// Pad keys 196..223 with -3e4 (exp -> 0). grid (56, HEADS) x 256.
// ===========================================================================
__global__ __launch_bounds__(256) void k_pbt(const float* __restrict__ pb) {
  const int h = blockIdx.y;
  const int key = blockIdx.x * 4 + (threadIdx.x >> 6);
  const int q = threadIdx.x & 63;
  float v = -30000.0f;
  if (key < NPOS) v = pb[((size_t)(h * 64 + q)) * NPOS + key];
  g_pbt[((size_t)(h * NPAD) + key) * 64 + q] = v;
}

// ===========================================================================
// k_xt: x[b][c][p] f32 -> xt[b*NP+p][c] bf16, 16B-granule XOR-swizzled:
// granule g of row r stored at g ^ (r&7). Consumed only by k_proj2, which
// reads with the same XOR (both-sides swizzle so global_load_lds stays linear).
// ===========================================================================
__global__ __launch_bounds__(256) void k_xt(const float* __restrict__ x,
                                            ushort* __restrict__ xt) {
  __shared__ __align__(16) ushort ls[64][66];
  const int b = blockIdx.z, p0 = blockIdx.x * 64, c0 = blockIdx.y * 64;
  const int by8 = blockIdx.y * 8;
  const int tid = threadIdx.x;
  #pragma unroll
  for (int it = 0; it < 4; ++it) {
    int i = it * 256 + tid;
    int c = i >> 4, ps = (i & 15) * 4;
    float4 v = *reinterpret_cast<const float4*>(x + ((size_t)(b * NC + c0 + c)) * NP + p0 + ps);
    ls[ps + 0][c] = f2bf(v.x);
    ls[ps + 1][c] = f2bf(v.y);
    ls[ps + 2][c] = f2bf(v.z);
    ls[ps + 3][c] = f2bf(v.w);
  }
  __syncthreads();
  #pragma unroll
  for (int it = 0; it < 2; ++it) {
    int i = it * 256 + tid;
    int p = i >> 3, gl = i & 7;
    Frag o;
    #pragma unroll
    for (int j = 0; j < 8; ++j) o.us[j] = ls[p][gl * 8 + j];
    // row&7 == p&7 (p0, b*NP multiples of 8); swizzle granule within row
    int gph = by8 + (gl ^ (p & 7));
    *reinterpret_cast<uint4*>(xt + ((size_t)(b * NP) + p0 + p) * NC + gph * 8) = o.u4;
  }
}

// ===========================================================================
// k_proj2: qkv[row][oc] = sum_c xt[row][c] * wb[oc][c]. M=65536 rows.
// m97-style: 64KB linear LDS A-tile (whole K=256) filled via global_load_lds
// (the 128-row slab of xt is contiguous -> pure DMA memcpy). A-reads apply
// the source XOR swizzle -> conflict-free ds_read_b128. Single barrier pair.
// 4 waves 2x2 (64 rows x 128 oc each, acc 4x8).
// ===========================================================================
__global__ __launch_bounds__(256, 2) void k_proj2(const ushort* __restrict__ xt,
                                                  ushort* __restrict__ qkv) {
  __shared__ __align__(16) ushort As[128 * 256];   // 64 KB, linear
  const int row0 = blockIdx.x * 128;
  const int n0 = blockIdx.y * 256;
  const int tid = threadIdx.x, lane = tid & 63, wid = tid >> 6;
  const int quad = lane >> 4, lc = lane & 15;
  // stage 128x256 bf16 (64 KB): 16 x global_load_lds_dwordx4 per thread
  const ushort* gs = xt + (size_t)row0 * NC;
  #pragma unroll
  for (int it = 0; it < 16; ++it) {
    int f = it * 256 + tid;
    gload_lds16(gs + (size_t)f * 8, As + f * 8);
  }
  __syncthreads();
  const int wm = (wid & 1) * 64, wn = (wid >> 1) * 128;
  f32x4 acc[4][8] = {};
  #pragma unroll
  for (int ks = 0; ks < 8; ++ks) {
    const int k0 = ks * 32 + quad * 8;
    Frag a[4];
    #pragma unroll
    for (int mt = 0; mt < 4; ++mt) {
      int row = wm + mt * 16 + lc;                 // row&7 == lc&7
      int gk = (ks * 4 + quad) ^ (lc & 7);         // undo source swizzle
      a[mt].u4 = *reinterpret_cast<const uint4*>(&As[row * 256 + gk * 8]);
    }
    #pragma unroll
    for (int ng = 0; ng < 2; ++ng) {
      Frag bb[4];
      #pragma unroll
      for (int j = 0; j < 4; ++j) {
        int oc = n0 + wn + (ng * 4 + j) * 16 + lc;
        bb[j].u4 = *reinterpret_cast<const uint4*>(g_wb + (size_t)oc * NC + k0);
      }
      #pragma unroll
      for (int mt = 0; mt < 4; ++mt)
        #pragma unroll
        for (int j = 0; j < 4; ++j)
          acc[mt][ng * 4 + j] = __builtin_amdgcn_mfma_f32_16x16x32_bf16(
              a[mt].b8, bb[j].b8, acc[mt][ng * 4 + j], 0, 0, 0);
    }
  }
  __syncthreads();
  // epilogue: acc -> As bf16 (same XOR swizzle -> spread write banks),
  // then coalesced uint4 stores
  #pragma unroll
  for (int mt = 0; mt < 4; ++mt)
    #pragma unroll
    for (int nn = 0; nn < 8; ++nn) {
      int row = wm + mt * 16 + quad * 4;
      #pragma unroll
      for (int r = 0; r < 4; ++r) {
        int rr = row + r;
        int col = wn + nn * 16 + lc;
        As[rr * 256 + (((col >> 3) ^ (rr & 7)) * 8) + (col & 7)] = f2bf(acc[mt][nn][r]);
      }
    }
  __syncthreads();
  #pragma unroll
  for (int it = 0; it < 16; ++it) {
    int i = it * 256 + tid;
    int r = i >> 5, g = i & 31;
    uint4 u = *reinterpret_cast<const uint4*>(&As[r * 256 + ((g ^ (r & 7)) * 8)]);
    *reinterpret_cast<uint4*>(qkv + ((size_t)(row0 + r)) * NOC + n0 + g * 8) = u;
  }
}

// ===========================================================================
// k_attn_f2: one wg per (b, block, head); 4 waves x 16 queries.
// LDS 36 KB -> 4 wg/CU (osh overlays ksh after QK phase).
// Softmax bias from g_pbt: 14 coalesced float4 loads/lane, no bounds
// check (padded keys give exp(-3e4)=0; ksh pad rows are zeroed).
// ===========================================================================
__global__ __launch_bounds__(256) void k_attn_f2(const ushort* __restrict__ qkv,
                                                 float* __restrict__ out) {
  __shared__ __align__(16) ushort ksh[NPAD][40];    // 17920 B; osh overlays
  __shared__ __align__(16) ushort vth[32][232];     // [d][key^swz]
  __shared__ __align__(16) ushort psh[4][16][32];   // per-wave P slab
  float (*osh)[33] = reinterpret_cast<float(*)[33]>(&ksh[0][0]);  // 8448 B
  const int b = blockIdx.z, h = blockIdx.y, blk = blockIdx.x;
  const int by = blk >> 3, bx = blk & 7;
  const int tid = threadIdx.x, lane = tid & 63, w = tid >> 6;
  const int quad = lane >> 4, lc = lane & 15;

  // q A-fragment straight from qkv: A[m=lc][k=quad*8+j]
  Frag aq;
  {
    int q = w * 16 + lc;
    int py = by * 8 + (q >> 3), px = bx * 8 + (q & 7);
    aq.u4 = *reinterpret_cast<const uint4*>(
        qkv + ((size_t)(b * NP + py * NW + px)) * NOC + h * 32 + quad * 8);
  }

  // stage KV window: 224 pos x 8 segs; segs 0..3 -> k, 4..7 -> v^T (swizzled)
  for (int it = 0; it < 7; ++it) {
    int i = it * 256 + tid;
    int pos = i >> 3, seg = i & 7;
    Frag v;
    v.u4 = make_uint4(0u, 0u, 0u, 0u);
    if (pos < NPOS) {
      int wy = pos / WIN;
      int wx = pos - wy * WIN;
      int yq = by * 8 - 3 + wy, xx = bx * 8 - 3 + wx;
      if ((unsigned)yq < (unsigned)NH && (unsigned)xx < (unsigned)NW)
        v.u4 = *reinterpret_cast<const uint4*>(
            qkv + ((size_t)(b * NP + yq * NW + xx)) * NOC + 256 + h * 64 + seg * 8);
    }
    if (seg < 4) {
      *reinterpret_cast<uint4*>(&ksh[pos][seg * 8]) = v.u4;
    } else {
      int d0 = (seg - 4) * 8;
      int cp = pos ^ ((seg - 4) << 3);   // XOR swizzle on key index
      #pragma unroll
      for (int j = 0; j < 8; ++j) vth[d0 + j][cp] = v.us[j];
    }
  }
  __syncthreads();

  // S = q k^T : 14 n-tiles of 16 keys
  f32x4 s[14];
  #pragma unroll
  for (int nt = 0; nt < 14; ++nt) {
    Frag bk;
    bk.u4 = *reinterpret_cast<const uint4*>(&ksh[nt * 16 + lc][quad * 8]);
    f32x4 z = {0.f, 0.f, 0.f, 0.f};
    s[nt] = __builtin_amdgcn_mfma_f32_16x16x32_bf16(aq.b8, bk.b8, z, 0, 0, 0);
  }

  const float scale = 0.17677669529663687f;  // 1/sqrt(32)
  const int qi = w * 16 + quad * 4;          // C-layout row = quad*4 + r
  const float* __restrict__ pbh = g_pbt + (size_t)h * (NPAD * 64);
  float lsum[4] = {0.f, 0.f, 0.f, 0.f};
  #pragma unroll
  for (int nt = 0; nt < 14; ++nt) {
    int col = nt * 16 + lc;
    float4 bv = *reinterpret_cast<const float4*>(pbh + col * 64 + qi);
    #pragma unroll
    for (int r = 0; r < 4; ++r) {
      float p = __expf(s[nt][r] * scale + (&bv.x)[r]);
      s[nt][r] = p;
      lsum[r] += p;
    }
  }

  // O = P V : 7 slabs of 32 keys, P round-tripped per slab (wave-private)
  f32x4 o[2] = {};
  #pragma unroll
  for (int kt = 0; kt < 7; ++kt) {
    #pragma unroll
    for (int t = 0; t < 2; ++t)
      #pragma unroll
      for (int r = 0; r < 4; ++r)
        psh[w][quad * 4 + r][t * 16 + lc] = f2bf(s[2 * kt + t][r]);
    Frag ap;
    ap.u4 = *reinterpret_cast<const uint4*>(&psh[w][lc][quad * 8]);
    #pragma unroll
    for (int t = 0; t < 2; ++t) {
      int d = t * 16 + lc;
      int g = (kt * 4 + quad) ^ ((d >> 3) & 3);
      Frag bv;
      bv.u4 = *reinterpret_cast<const uint4*>(&vth[d][g * 8]);
      o[t] = __builtin_amdgcn_mfma_f32_16x16x32_bf16(ap.b8, bv.b8, o[t], 0, 0, 0);
    }
  }

  #pragma unroll
  for (int m = 1; m < 16; m <<= 1)
    #pragma unroll
    for (int r = 0; r < 4; ++r) lsum[r] += __shfl_xor(lsum[r], m);
  float rinv[4];
  #pragma unroll
  for (int r = 0; r < 4; ++r) rinv[r] = 1.0f / lsum[r];

  __syncthreads();   // all waves done reading ksh before osh overlay write
  #pragma unroll
  for (int t = 0; t < 2; ++t)
    #pragma unroll
    for (int r = 0; r < 4; ++r)
      osh[w * 16 + quad * 4 + r][t * 16 + lc] = o[t][r] * rinv[r];
  __syncthreads();

  // write: out[b][h*32+d][by*8+yy][bx*8..+8], f32, two float4 per lane
  {
    int d = tid >> 3, yy = tid & 7;
    float4 o0, o1;
    o0.x = osh[yy * 8 + 0][d]; o0.y = osh[yy * 8 + 1][d];
    o0.z = osh[yy * 8 + 2][d]; o0.w = osh[yy * 8 + 3][d];
    o1.x = osh[yy * 8 + 4][d]; o1.y = osh[yy * 8 + 5][d];
    o1.z = osh[yy * 8 + 6][d]; o1.w = osh[yy * 8 + 7][d];
    float* op = out + ((size_t)(b * NC + h * 32 + d) * NH + by * 8 + yy) * NW + bx * 8;
    *reinterpret_cast<float4*>(op) = o0;
    *reinterpret_cast<float4*>(op + 4) = o1;
  }
}

// ===========================================================================
// MID FALLBACK (96 MiB <= ws < 128 MiB): R4 k_proj (proven) + k_attn_f2
// ===========================================================================
__global__ __launch_bounds__(256) void k_proj_r4(const float* __restrict__ x,
                                                 const float* __restrict__ wq,
                                                 const float* __restrict__ wkv,
                                                 ushort* __restrict__ qkv) {
  __shared__ __align__(16) ushort As[64][264];
  const int b = blockIdx.z, y = blockIdx.x;
  const int n0 = blockIdx.y * 256;
  const int tid = threadIdx.x, lane = tid & 63, wid = tid >> 6;
  const int quad = lane >> 4, lc = lane & 15;
  #pragma unroll
  for (int it = 0; it < 16; ++it) {
    int i = it * 256 + tid;
    int c = i >> 4, xs = (i & 15) * 4;
    float4 v = *reinterpret_cast<const float4*>(x + ((size_t)(b * NC + c)) * NP + y * NW + xs);
    #pragma unroll
    for (int j = 0; j < 4; ++j) {
      int row = xs + j;
      float f = (j == 0) ? v.x : (j == 1) ? v.y : (j == 2) ? v.z : v.w;
      As[row][c ^ ((((row >> 2) & 3)) << 3)] = f2bf(f);
    }
  }
  __syncthreads();
  const int wm = (wid & 1) * 32, wn = (wid >> 1) * 128;
  const int swz = ((lc >> 2) & 3) << 3;
  f32x4 acc[2][8] = {};
  #pragma unroll
  for (int ks = 0; ks < 8; ++ks) {
    const int k0 = ks * 32 + quad * 8;
    Frag a0, a1;
    a0.u4 = *reinterpret_cast<const uint4*>(&As[wm + lc][k0 ^ swz]);
    a1.u4 = *reinterpret_cast<const uint4*>(&As[wm + 16 + lc][k0 ^ swz]);
    #pragma unroll
    for (int nh = 0; nh < 2; ++nh) {
      bf16x8 bb[4];
      #pragma unroll
      for (int nt = 0; nt < 4; ++nt) {
        int oc = n0 + wn + nh * 64 + nt * 16 + lc;
        const float* wp = (oc < 256) ? (wq + (size_t)oc * NC) : (wkv + (size_t)(oc - 256) * NC);
        bb[nt] = load_bf8(wp + k0);
      }
      #pragma unroll
      for (int nt = 0; nt < 4; ++nt) {
        acc[0][nh * 4 + nt] = __builtin_amdgcn_mfma_f32_16x16x32_bf16(a0.b8, bb[nt], acc[0][nh * 4 + nt], 0, 0, 0);
        acc[1][nh * 4 + nt] = __builtin_amdgcn_mfma_f32_16x16x32_bf16(a1.b8, bb[nt], acc[1][nh * 4 + nt], 0, 0, 0);
      }
    }
  }
  __syncthreads();
  #pragma unroll
  for (int mt = 0; mt < 2; ++mt)
    #pragma unroll
    for (int nn = 0; nn < 8; ++nn)
      #pragma unroll
      for (int r = 0; r < 4; ++r)
        As[wm + mt * 16 + quad * 4 + r][wn + nn * 16 + lc] = f2bf(acc[mt][nn][r]);
  __syncthreads();
  #pragma unroll
  for (int v8 = 0; v8 < 8; ++v8) {
    int flat = v8 * 256 + tid;
    int p = flat >> 5, seg = flat & 31;
    uint4 u = *reinterpret_cast<const uint4*>(&As[p][seg * 8]);
    *reinterpret_cast<uint4*>(qkv + ((size_t)(b * NP) + y * NW + p) * NOC + n0 + seg * 8) = u;
  }
}

// ===========================================================================
// LOW FALLBACK (ws < 96 MiB): Round-3 kernels, proven correct
// ===========================================================================
__global__ __launch_bounds__(256) void k_kv(const float* __restrict__ x,
                                            const float* __restrict__ wkv,
                                            ushort* __restrict__ kvb) {
  __shared__ __align__(16) ushort As[64][264];
  const int b = blockIdx.z;
  const int y = blockIdx.x;
  const int n0 = blockIdx.y * 128;
  const int tid = threadIdx.x;
  const int lane = tid & 63, wid = tid >> 6;
  const int quad = lane >> 4, lc = lane & 15;
  #pragma unroll
  for (int it = 0; it < 16; ++it) {
    int i = it * 256 + tid;
    int c = i >> 4, xs = (i & 15) * 4;
    float4 v = *reinterpret_cast<const float4*>(x + ((size_t)(b * NC + c)) * NP + y * NW + xs);
    As[xs + 0][c] = f2bf(v.x);
    As[xs + 1][c] = f2bf(v.y);
    As[xs + 2][c] = f2bf(v.z);
    As[xs + 3][c] = f2bf(v.w);
  }
  __syncthreads();
  const int wm = (wid & 1) * 32, wn = (wid >> 1) * 64;
  f32x4 acc[2][4] = {};
  #pragma unroll
  for (int ks = 0; ks < 8; ++ks) {
    const int k0 = ks * 32 + quad * 8;
    Frag a[2];
    bf16x8 bb[4];
    #pragma unroll
    for (int mt = 0; mt < 2; ++mt)
      a[mt].u4 = *reinterpret_cast<const uint4*>(&As[wm + mt * 16 + lc][k0]);
    #pragma unroll
    for (int nt = 0; nt < 4; ++nt) {
      int oc = n0 + wn + nt * 16 + lc;
      bb[nt] = load_bf8(wkv + (size_t)oc * NC + k0);
    }
    #pragma unroll
    for (int mt = 0; mt < 2; ++mt)
      #pragma unroll
      for (int nt = 0; nt < 4; ++nt)
        acc[mt][nt] = __builtin_amdgcn_mfma_f32_16x16x32_bf16(a[mt].b8, bb[nt], acc[mt][nt], 0, 0, 0);
  }
  #pragma unroll
  for (int mt = 0; mt < 2; ++mt) {
    #pragma unroll
    for (int r = 0; r < 4; ++r) {
      int pl = wm + mt * 16 + quad * 4 + r;
      #pragma unroll
      for (int nt = 0; nt < 4; ++nt) {
        int oc = n0 + wn + nt * 16 + lc;
        kvb[((size_t)(b * NP + y * NW + pl)) * NKV + oc] = f2bf(acc[mt][nt][r]);
      }
    }
  }
}

__global__ __launch_bounds__(256) void k_attn_v3(const float* __restrict__ x,
                                                 const float* __restrict__ wq,
                                                 const ushort* __restrict__ kvb,
                                                 const float* __restrict__ pbias,
                                                 float* __restrict__ out) {
  __shared__ __align__(16) ushort ksh[NPAD][40];
  __shared__ __align__(16) ushort vth[32][232];
  __shared__ __align__(16) ushort psh[4][16][232];
  __shared__ __align__(16) ushort qsh[4][16][32];
  __shared__ __align__(16) float osh[64][33];
  const int b = blockIdx.z, h = blockIdx.y, blk = blockIdx.x;
  const int by = blk >> 3, bx = blk & 7;
  const int tid = threadIdx.x, lane = tid & 63, w = tid >> 6;
  const int quad = lane >> 4, lc = lane & 15;

  for (int it = 0; it < 7; ++it) {
    int i = it * 256 + tid;
    int pos = i >> 3, seg = i & 7;
    Frag v;
    v.u4 = make_uint4(0u, 0u, 0u, 0u);
    if (pos < NPOS) {
      int wy = pos / WIN;
      int wx = pos - wy * WIN;
      int yq = by * 8 - 3 + wy, xx = bx * 8 - 3 + wx;
      if ((unsigned)yq < (unsigned)NH && (unsigned)xx < (unsigned)NW)
        v.u4 = *reinterpret_cast<const uint4*>(
            kvb + ((size_t)(b * NP + yq * NW + xx)) * NKV + h * 64 + seg * 8);
    }
    if (seg < 4) {
      *reinterpret_cast<uint4*>(&ksh[pos][seg * 8]) = v.u4;
    } else {
      int d0 = (seg - 4) * 8;
      #pragma unroll
      for (int j = 0; j < 8; ++j) vth[d0 + j][pos] = v.us[j];
    }
  }

  f32x4 qacc[2] = {};
  {
    const int q = w * 16 + lc;
    const size_t p = (size_t)(by * 8 + (q >> 3)) * NW + bx * 8 + (q & 7);
    #pragma unroll
    for (int ks = 0; ks < 8; ++ks) {
      const int k0 = ks * 32 + quad * 8;
      Frag ax;
      #pragma unroll
      for (int j = 0; j < 8; ++j)
        ax.us[j] = f2bf(x[((size_t)(b * NC + k0 + j)) * NP + p]);
      bf16x8 bw0 = load_bf8(wq + (size_t)(h * 32 + lc) * NC + k0);
      bf16x8 bw1 = load_bf8(wq + (size_t)(h * 32 + 16 + lc) * NC + k0);
      qacc[0] = __builtin_amdgcn_mfma_f32_16x16x32_bf16(ax.b8, bw0, qacc[0], 0, 0, 0);
      qacc[1] = __builtin_amdgcn_mfma_f32_16x16x32_bf16(ax.b8, bw1, qacc[1], 0, 0, 0);
    }
  }
  #pragma unroll
  for (int t = 0; t < 2; ++t)
    #pragma unroll
    for (int r = 0; r < 4; ++r)
      qsh[w][quad * 4 + r][t * 16 + lc] = f2bf(qacc[t][r]);
  Frag aq;
  aq.u4 = *reinterpret_cast<const uint4*>(&qsh[w][lc][quad * 8]);

  __syncthreads();

  f32x4 s[14];
  #pragma unroll
  for (int nt = 0; nt < 14; ++nt) {
    Frag bk;
    bk.u4 = *reinterpret_cast<const uint4*>(&ksh[nt * 16 + lc][quad * 8]);
    f32x4 z = {0.f, 0.f, 0.f, 0.f};
    s[nt] = __builtin_amdgcn_mfma_f32_16x16x32_bf16(aq.b8, bk.b8, z, 0, 0, 0);
  }

  const float scale = 0.17677669529663687f;
  const int qi = w * 16 + quad * 4;
  float lsum[4] = {0.f, 0.f, 0.f, 0.f};
  #pragma unroll
  for (int nt = 0; nt < 14; ++nt) {
    int col = nt * 16 + lc;
    #pragma unroll
    for (int r = 0; r < 4; ++r) {
      float p = 0.f;
      if (col < NPOS)
        p = __expf(s[nt][r] * scale + pbias[(size_t)(h * 64 + qi + r) * NPOS + col]);
      s[nt][r] = p;
      lsum[r] += p;
    }
  }
  #pragma unroll
  for (int m = 1; m < 16; m <<= 1) {
    #pragma unroll
    for (int r = 0; r < 4; ++r) lsum[r] += __shfl_xor(lsum[r], m);
  }
  #pragma unroll
  for (int nt = 0; nt < 14; ++nt) {
    #pragma unroll
    for (int r = 0; r < 4; ++r) psh[w][quad * 4 + r][nt * 16 + lc] = f2bf(s[nt][r]);
  }
  f32x4 o[2] = {};
  #pragma unroll
  for (int kt = 0; kt < 7; ++kt) {
    Frag ap;
    ap.u4 = *reinterpret_cast<const uint4*>(&psh[w][lc][kt * 32 + quad * 8]);
    #pragma unroll
    for (int t = 0; t < 2; ++t) {
      Frag bv;
      bv.u4 = *reinterpret_cast<const uint4*>(&vth[t * 16 + lc][kt * 32 + quad * 8]);
      o[t] = __builtin_amdgcn_mfma_f32_16x16x32_bf16(ap.b8, bv.b8, o[t], 0, 0, 0);
    }
  }
  #pragma unroll
  for (int t = 0; t < 2; ++t)
    #pragma unroll
    for (int r = 0; r < 4; ++r)
      osh[w * 16 + quad * 4 + r][t * 16 + lc] = o[t][r] / lsum[r];
  __syncthreads();
  {
    int d = tid >> 3, yy = tid & 7;
    float4 o0, o1;
    o0.x = osh[yy * 8 + 0][d]; o0.y = osh[yy * 8 + 1][d];
    o0.z = osh[yy * 8 + 2][d]; o0.w = osh[yy * 8 + 3][d];
    o1.x = osh[yy * 8 + 4][d]; o1.y = osh[yy * 8 + 5][d];
    o1.z = osh[yy * 8 + 6][d]; o1.w = osh[yy * 8 + 7][d];
    float* op = out + ((size_t)(b * NC + h * 32 + d) * NH + by * 8 + yy) * NW + bx * 8;
    *reinterpret_cast<float4*>(op) = o0;
    *reinterpret_cast<float4*>(op + 4) = o1;
  }
}

// ---------------------------------------------------------------------------
extern "C" void kernel_launch(void* const* d_in, const int* in_sizes, int n_in,
                              void* d_out, int out_size, void* d_ws, size_t ws_size,
                              hipStream_t stream) {
  const float* x   = (const float*)d_in[0];  // (16,256,64,64) f32
  const float* wq  = (const float*)d_in[1];  // (256,256) f32
  const float* wkv = (const float*)d_in[2];  // (512,256) f32
  const float* pb  = (const float*)d_in[3];  // (8,64,196) f32
  float* outp = (float*)d_out;               // (16,256,64,64) f32

  const size_t qkv_bytes = (size_t)NB * NP * NOC * sizeof(ushort);  // 96 MiB
  const size_t xt_bytes  = (size_t)NB * NP * NC * sizeof(ushort);   // 32 MiB

  if (ws_size >= qkv_bytes + xt_bytes) {
    // FULL: wcast + pbias transpose + swizzled transpose + DMA-staged GEMM + attn
    ushort* qkv = (ushort*)d_ws;
    ushort* xt  = (ushort*)((char*)d_ws + qkv_bytes);
    k_wcast<<<dim3(NOC * NC / (256 * 8)), 256, 0, stream>>>(wq, wkv);
    k_pbt<<<dim3(NPAD / 4, HEADS), 256, 0, stream>>>(pb);
    k_xt<<<dim3(NP / 64, NC / 64, NB), 256, 0, stream>>>(x, xt);
    k_proj2<<<dim3(NB * NP / 128, 3), 256, 0, stream>>>(xt, qkv);
    k_attn_f2<<<dim3(64, HEADS, NB), 256, 0, stream>>>(qkv, outp);
  } else if (ws_size >= qkv_bytes) {
    ushort* qkv = (ushort*)d_ws;
    k_pbt<<<dim3(NPAD / 4, HEADS), 256, 0, stream>>>(pb);
    k_proj_r4<<<dim3(NH, 3, NB), 256, 0, stream>>>(x, wq, wkv, qkv);
    k_attn_f2<<<dim3(64, HEADS, NB), 256, 0, stream>>>(qkv, outp);
  } else {
    ushort* kvb = (ushort*)d_ws;               // 64 MiB
    k_kv<<<dim3(NH, NKV / 128, NB), 256, 0, stream>>>(x, wkv, kvb);
    k_attn_v3<<<dim3(64, HEADS, NB), 256, 0, stream>>>(x, wq, kvb, pb, outp);
  }
}

// Round 4
// 297.744 us; speedup vs baseline: 1.0183x; 1.0183x over previous
//
#include <hip/hip_runtime.h>
#include <hip/hip_bf16.h>
#include <stdint.h>

// Problem constants (B,C,H,W)=(16,256,64,64), HEADS=8, BS=8, HALO=3
#define HEADS 8
#define WIN 14
#define NPOS 196          // WIN*WIN
#define NPAD 224          // padded key count = 7*32
#define NB 16
#define NC 256
#define NH 64
#define NW 64
#define NP 4096           // NH*NW
#define NKV 512           // kv channels (fallback layout)
#define NOC 768           // q(256) + kv(512) channels

typedef __bf16 bf16_t;
typedef bf16_t bf16x8 __attribute__((ext_vector_type(8)));
typedef float f32x4 __attribute__((ext_vector_type(4)));

union Frag {
  uint4 u4;
  bf16x8 b8;
  ushort us[8];
};

__device__ __forceinline__ ushort f2bf(float f) {
  bf16_t h = (bf16_t)f;
  return __builtin_bit_cast(ushort, h);
}
__device__ __forceinline__ bf16x8 load_bf8(const float* __restrict__ p) {
  float4 a = *reinterpret_cast<const float4*>(p);
  float4 b = *reinterpret_cast<const float4*>(p + 4);
  bf16x8 r;
  r[0] = (bf16_t)a.x; r[1] = (bf16_t)a.y; r[2] = (bf16_t)a.z; r[3] = (bf16_t)a.w;
  r[4] = (bf16_t)b.x; r[5] = (bf16_t)b.y; r[6] = (bf16_t)b.z; r[7] = (bf16_t)b.w;
  return r;
}

// direct global->LDS DMA, 16B per lane
__device__ __forceinline__ void gload_lds16(const ushort* g, ushort* l) {
#if __has_builtin(__builtin_amdgcn_global_load_lds)
  __builtin_amdgcn_global_load_lds(
      (const __attribute__((address_space(1))) unsigned int*)(const void*)g,
      (__attribute__((address_space(3))) unsigned int*)(void*)l, 16, 0, 0);
#else
  *reinterpret_cast<uint4*>(l) = *reinterpret_cast<const uint4*>(g);
#endif
}

// bf16 weights, converted once per launch (same data every call)
__device__ ushort g_wb[NOC * NC];
// key-padded, log2e-prescaled pos bias: [h*64+q][key(224)], pad keys = -1e5
__device__ float g_pbt[HEADS * 64 * NPAD];

// ===========================================================================
// k_prep: wg<96 -> weight cast to g_wb; wg>=96 -> pbias pad+prescale to g_pbt.
// grid 608 x 256.
// ===========================================================================
__global__ __launch_bounds__(256) void k_prep(const float* __restrict__ wq,
                                              const float* __restrict__ wkv,
                                              const float* __restrict__ pb) {
  const int wg = blockIdx.x;
  if (wg < 96) {
    int idx = (wg * 256 + threadIdx.x) * 8;
    int oc = idx >> 8, c = idx & 255;
    const float* src = (oc < 256) ? (wq + (size_t)oc * NC + c)
                                  : (wkv + (size_t)(oc - 256) * NC + c);
    Frag v;
    v.b8 = load_bf8(src);
    *reinterpret_cast<uint4*>(g_wb + idx) = v.u4;
  } else {
    int row = wg - 96;               // h*64+q, 0..511
    int key = threadIdx.x;
    if (key < NPAD) {
      float v = -100000.0f;
      if (key < NPOS) v = pb[(size_t)row * NPOS + key] * 1.4426950408889634f;
      g_pbt[(size_t)row * NPAD + key] = v;
    }
  }
}

// ===========================================================================
// k_xt: x[b][c][p] f32 -> xt[b*NP+p][c] bf16, 16B-granule XOR-swizzled:
// granule g of row r stored at g ^ (r&7). Consumed only by k_proj2, which
// reads with the same XOR (both-sides swizzle so global_load_lds stays linear).
// ===========================================================================
__global__ __launch_bounds__(256) void k_xt(const float* __restrict__ x,
                                            ushort* __restrict__ xt) {
  __shared__ __align__(16) ushort ls[64][66];
  const int b = blockIdx.z, p0 = blockIdx.x * 64, c0 = blockIdx.y * 64;
  const int by8 = blockIdx.y * 8;
  const int tid = threadIdx.x;
  #pragma unroll
  for (int it = 0; it < 4; ++it) {
    int i = it * 256 + tid;
    int c = i >> 4, ps = (i & 15) * 4;
    float4 v = *reinterpret_cast<const float4*>(x + ((size_t)(b * NC + c0 + c)) * NP + p0 + ps);
    ls[ps + 0][c] = f2bf(v.x);
    ls[ps + 1][c] = f2bf(v.y);
    ls[ps + 2][c] = f2bf(v.z);
    ls[ps + 3][c] = f2bf(v.w);
  }
  __syncthreads();
  #pragma unroll
  for (int it = 0; it < 2; ++it) {
    int i = it * 256 + tid;
    int p = i >> 3, gl = i & 7;
    Frag o;
    #pragma unroll
    for (int j = 0; j < 8; ++j) o.us[j] = ls[p][gl * 8 + j];
    // row&7 == p&7 (p0, b*NP multiples of 8); swizzle granule within row
    int gph = by8 + (gl ^ (p & 7));
    *reinterpret_cast<uint4*>(xt + ((size_t)(b * NP) + p0 + p) * NC + gph * 8) = o.u4;
  }
}

// ===========================================================================
// k_proj2: qkv[row][oc] = sum_c xt[row][c] * wb[oc][c]. M=65536 rows.
// 64KB linear LDS A-tile (whole K=256) filled via global_load_lds; A-reads
// undo the source XOR swizzle -> conflict-free ds_read_b128. One barrier pair.
// ===========================================================================
__global__ __launch_bounds__(256, 2) void k_proj2(const ushort* __restrict__ xt,
                                                  ushort* __restrict__ qkv) {
  __shared__ __align__(16) ushort As[128 * 256];   // 64 KB, linear
  const int row0 = blockIdx.x * 128;
  const int n0 = blockIdx.y * 256;
  const int tid = threadIdx.x, lane = tid & 63, wid = tid >> 6;
  const int quad = lane >> 4, lc = lane & 15;
  const ushort* gs = xt + (size_t)row0 * NC;
  #pragma unroll
  for (int it = 0; it < 16; ++it) {
    int f = it * 256 + tid;
    gload_lds16(gs + (size_t)f * 8, As + f * 8);
  }
  __syncthreads();
  const int wm = (wid & 1) * 64, wn = (wid >> 1) * 128;
  f32x4 acc[4][8] = {};
  #pragma unroll
  for (int ks = 0; ks < 8; ++ks) {
    const int k0 = ks * 32 + quad * 8;
    Frag a[4];
    #pragma unroll
    for (int mt = 0; mt < 4; ++mt) {
      int row = wm + mt * 16 + lc;                 // row&7 == lc&7
      int gk = (ks * 4 + quad) ^ (lc & 7);         // undo source swizzle
      a[mt].u4 = *reinterpret_cast<const uint4*>(&As[row * 256 + gk * 8]);
    }
    #pragma unroll
    for (int ng = 0; ng < 2; ++ng) {
      Frag bb[4];
      #pragma unroll
      for (int j = 0; j < 4; ++j) {
        int oc = n0 + wn + (ng * 4 + j) * 16 + lc;
        bb[j].u4 = *reinterpret_cast<const uint4*>(g_wb + (size_t)oc * NC + k0);
      }
      #pragma unroll
      for (int mt = 0; mt < 4; ++mt)
        #pragma unroll
        for (int j = 0; j < 4; ++j)
          acc[mt][ng * 4 + j] = __builtin_amdgcn_mfma_f32_16x16x32_bf16(
              a[mt].b8, bb[j].b8, acc[mt][ng * 4 + j], 0, 0, 0);
    }
  }
  __syncthreads();
  #pragma unroll
  for (int mt = 0; mt < 4; ++mt)
    #pragma unroll
    for (int nn = 0; nn < 8; ++nn) {
      int row = wm + mt * 16 + quad * 4;
      #pragma unroll
      for (int r = 0; r < 4; ++r) {
        int rr = row + r;
        int col = wn + nn * 16 + lc;
        As[rr * 256 + (((col >> 3) ^ (rr & 7)) * 8) + (col & 7)] = f2bf(acc[mt][nn][r]);
      }
    }
  __syncthreads();
  #pragma unroll
  for (int it = 0; it < 16; ++it) {
    int i = it * 256 + tid;
    int r = i >> 5, g = i & 31;
    uint4 u = *reinterpret_cast<const uint4*>(&As[r * 256 + ((g ^ (r & 7)) * 8)]);
    *reinterpret_cast<uint4*>(qkv + ((size_t)(row0 + r)) * NOC + n0 + g * 8) = u;
  }
}

// ===========================================================================
// k_attn_f2: 1D grid 8192, XCD-swizzled (contiguous chunk per XCD; h fastest
// -> all heads of a block + adjacent blocks hit the same L2 lines).
// 4 waves x 16 queries; proven vth XOR-swizzle V path (round-0, 110us).
// Bias: padded log2e-prescaled g_pbt, coalesced scalar loads, no predicate;
// softmax = fma + v_exp. Staging loop unrolled for MLP. setprio on MFMA.
// LDS 36 KB -> 4 wg/CU (osh overlays ksh after QK phase).
// ===========================================================================
__global__ __launch_bounds__(256) void k_attn_f2(const ushort* __restrict__ qkv,
                                                 float* __restrict__ out) {
  __shared__ __align__(16) ushort ksh[NPAD][40];    // 17920 B; osh overlays
  __shared__ __align__(16) ushort vth[32][232];     // [d][key^swz]
  __shared__ __align__(16) ushort psh[4][16][32];   // per-wave P slab
  float (*osh)[33] = reinterpret_cast<float(*)[33]>(&ksh[0][0]);  // 8448 B
  // bijective XCD swizzle: 8192 wg = 8 xcd x 1024; h fastest, then blk, then b
  const int orig = blockIdx.x;
  const int wgid = (orig & 7) * 1024 + (orig >> 3);
  const int h = wgid & 7;
  const int blk = (wgid >> 3) & 63;
  const int b = wgid >> 9;
  const int by = blk >> 3, bx = blk & 7;
  const int tid = threadIdx.x, lane = tid & 63, w = tid >> 6;
  const int quad = lane >> 4, lc = lane & 15;

  // q A-fragment straight from qkv: A[m=lc][k=quad*8+j]
  Frag aq;
  {
    int q = w * 16 + lc;
    int py = by * 8 + (q >> 3), px = bx * 8 + (q & 7);
    aq.u4 = *reinterpret_cast<const uint4*>(
        qkv + ((size_t)(b * NP + py * NW + px)) * NOC + h * 32 + quad * 8);
  }

  // stage KV window: 224 pos x 8 segs; segs 0..3 -> k, 4..7 -> v^T (swizzled)
  #pragma unroll
  for (int it = 0; it < 7; ++it) {
    int i = it * 256 + tid;
    int pos = i >> 3, seg = i & 7;
    Frag v;
    v.u4 = make_uint4(0u, 0u, 0u, 0u);
    if (pos < NPOS) {
      int wy = pos / WIN;
      int wx = pos - wy * WIN;
      int yq = by * 8 - 3 + wy, xx = bx * 8 - 3 + wx;
      if ((unsigned)yq < (unsigned)NH && (unsigned)xx < (unsigned)NW)
        v.u4 = *reinterpret_cast<const uint4*>(
            qkv + ((size_t)(b * NP + yq * NW + xx)) * NOC + 256 + h * 64 + seg * 8);
    }
    if (seg < 4) {
      *reinterpret_cast<uint4*>(&ksh[pos][seg * 8]) = v.u4;
    } else {
      int d0 = (seg - 4) * 8;
      int cp = pos ^ ((seg - 4) << 3);   // XOR swizzle on key index
      #pragma unroll
      for (int j = 0; j < 8; ++j) vth[d0 + j][cp] = v.us[j];
    }
  }
  __syncthreads();

  // S = q k^T : 14 n-tiles of 16 keys
  f32x4 s[14];
  __builtin_amdgcn_s_setprio(1);
  #pragma unroll
  for (int nt = 0; nt < 14; ++nt) {
    Frag bk;
    bk.u4 = *reinterpret_cast<const uint4*>(&ksh[nt * 16 + lc][quad * 8]);
    f32x4 z = {0.f, 0.f, 0.f, 0.f};
    s[nt] = __builtin_amdgcn_mfma_f32_16x16x32_bf16(aq.b8, bk.b8, z, 0, 0, 0);
  }
  __builtin_amdgcn_s_setprio(0);

  // softmax: p = exp2(s * (scale*log2e) + bias_pre)  [bias pre-scaled]
  const float ck = 0.17677669529663687f * 1.4426950408889634f;
  const int qi = w * 16 + quad * 4;          // C-layout row = quad*4 + r
  const float* __restrict__ pbh = g_pbt + (size_t)(h * 64) * NPAD;
  float lsum[4] = {0.f, 0.f, 0.f, 0.f};
  #pragma unroll
  for (int nt = 0; nt < 14; ++nt) {
    int col = nt * 16 + lc;
    #pragma unroll
    for (int r = 0; r < 4; ++r) {
      float p = exp2f(s[nt][r] * ck + pbh[(size_t)(qi + r) * NPAD + col]);
      s[nt][r] = p;
      lsum[r] += p;
    }
  }

  // O = P V : 7 slabs of 32 keys, P round-tripped per slab (wave-private)
  f32x4 o[2] = {};
  #pragma unroll
  for (int kt = 0; kt < 7; ++kt) {
    #pragma unroll
    for (int t = 0; t < 2; ++t)
      #pragma unroll
      for (int r = 0; r < 4; ++r)
        psh[w][quad * 4 + r][t * 16 + lc] = f2bf(s[2 * kt + t][r]);
    Frag ap;
    ap.u4 = *reinterpret_cast<const uint4*>(&psh[w][lc][quad * 8]);
    __builtin_amdgcn_s_setprio(1);
    #pragma unroll
    for (int t = 0; t < 2; ++t) {
      int d = t * 16 + lc;
      int g = (kt * 4 + quad) ^ ((d >> 3) & 3);
      Frag bv;
      bv.u4 = *reinterpret_cast<const uint4*>(&vth[d][g * 8]);
      o[t] = __builtin_amdgcn_mfma_f32_16x16x32_bf16(ap.b8, bv.b8, o[t], 0, 0, 0);
    }
    __builtin_amdgcn_s_setprio(0);
  }

  #pragma unroll
  for (int m = 1; m < 16; m <<= 1)
    #pragma unroll
    for (int r = 0; r < 4; ++r) lsum[r] += __shfl_xor(lsum[r], m);
  float rinv[4];
  #pragma unroll
  for (int r = 0; r < 4; ++r) rinv[r] = 1.0f / lsum[r];

  __syncthreads();   // all waves done reading ksh before osh overlay write
  #pragma unroll
  for (int t = 0; t < 2; ++t)
    #pragma unroll
    for (int r = 0; r < 4; ++r)
      osh[w * 16 + quad * 4 + r][t * 16 + lc] = o[t][r] * rinv[r];
  __syncthreads();

  // write: out[b][h*32+d][by*8+yy][bx*8..+8], f32, two float4 per lane
  {
    int d = tid >> 3, yy = tid & 7;
    float4 o0, o1;
    o0.x = osh[yy * 8 + 0][d]; o0.y = osh[yy * 8 + 1][d];
    o0.z = osh[yy * 8 + 2][d]; o0.w = osh[yy * 8 + 3][d];
    o1.x = osh[yy * 8 + 4][d]; o1.y = osh[yy * 8 + 5][d];
    o1.z = osh[yy * 8 + 6][d]; o1.w = osh[yy * 8 + 7][d];
    float* op = out + ((size_t)(b * NC + h * 32 + d) * NH + by * 8 + yy) * NW + bx * 8;
    *reinterpret_cast<float4*>(op) = o0;
    *reinterpret_cast<float4*>(op + 4) = o1;
  }
}

// ===========================================================================
// MID FALLBACK (96 MiB <= ws < 128 MiB): R4 k_proj (proven) + k_attn_f2
// ===========================================================================
__global__ __launch_bounds__(256) void k_proj_r4(const float* __restrict__ x,
                                                 const float* __restrict__ wq,
                                                 const float* __restrict__ wkv,
                                                 ushort* __restrict__ qkv) {
  __shared__ __align__(16) ushort As[64][264];
  const int b = blockIdx.z, y = blockIdx.x;
  const int n0 = blockIdx.y * 256;
  const int tid = threadIdx.x, lane = tid & 63, wid = tid >> 6;
  const int quad = lane >> 4, lc = lane & 15;
  #pragma unroll
  for (int it = 0; it < 16; ++it) {
    int i = it * 256 + tid;
    int c = i >> 4, xs = (i & 15) * 4;
    float4 v = *reinterpret_cast<const float4*>(x + ((size_t)(b * NC + c)) * NP + y * NW + xs);
    #pragma unroll
    for (int j = 0; j < 4; ++j) {
      int row = xs + j;
      float f = (j == 0) ? v.x : (j == 1) ? v.y : (j == 2) ? v.z : v.w;
      As[row][c ^ ((((row >> 2) & 3)) << 3)] = f2bf(f);
    }
  }
  __syncthreads();
  const int wm = (wid & 1) * 32, wn = (wid >> 1) * 128;
  const int swz = ((lc >> 2) & 3) << 3;
  f32x4 acc[2][8] = {};
  #pragma unroll
  for (int ks = 0; ks < 8; ++ks) {
    const int k0 = ks * 32 + quad * 8;
    Frag a0, a1;
    a0.u4 = *reinterpret_cast<const uint4*>(&As[wm + lc][k0 ^ swz]);
    a1.u4 = *reinterpret_cast<const uint4*>(&As[wm + 16 + lc][k0 ^ swz]);
    #pragma unroll
    for (int nh = 0; nh < 2; ++nh) {
      bf16x8 bb[4];
      #pragma unroll
      for (int nt = 0; nt < 4; ++nt) {
        int oc = n0 + wn + nh * 64 + nt * 16 + lc;
        const float* wp = (oc < 256) ? (wq + (size_t)oc * NC) : (wkv + (size_t)(oc - 256) * NC);
        bb[nt] = load_bf8(wp + k0);
      }
      #pragma unroll
      for (int nt = 0; nt < 4; ++nt) {
        acc[0][nh * 4 + nt] = __builtin_amdgcn_mfma_f32_16x16x32_bf16(a0.b8, bb[nt], acc[0][nh * 4 + nt], 0, 0, 0);
        acc[1][nh * 4 + nt] = __builtin_amdgcn_mfma_f32_16x16x32_bf16(a1.b8, bb[nt], acc[1][nh * 4 + nt], 0, 0, 0);
      }
    }
  }
  __syncthreads();
  #pragma unroll
  for (int mt = 0; mt < 2; ++mt)
    #pragma unroll
    for (int nn = 0; nn < 8; ++nn)
      #pragma unroll
      for (int r = 0; r < 4; ++r)
        As[wm + mt * 16 + quad * 4 + r][wn + nn * 16 + lc] = f2bf(acc[mt][nn][r]);
  __syncthreads();
  #pragma unroll
  for (int v8 = 0; v8 < 8; ++v8) {
    int flat = v8 * 256 + tid;
    int p = flat >> 5, seg = flat & 31;
    uint4 u = *reinterpret_cast<const uint4*>(&As[p][seg * 8]);
    *reinterpret_cast<uint4*>(qkv + ((size_t)(b * NP) + y * NW + p) * NOC + n0 + seg * 8) = u;
  }
}

// ===========================================================================
// LOW FALLBACK (ws < 96 MiB): Round-3 kernels, proven correct
// ===========================================================================
__global__ __launch_bounds__(256) void k_kv(const float* __restrict__ x,
                                            const float* __restrict__ wkv,
                                            ushort* __restrict__ kvb) {
  __shared__ __align__(16) ushort As[64][264];
  const int b = blockIdx.z;
  const int y = blockIdx.x;
  const int n0 = blockIdx.y * 128;
  const int tid = threadIdx.x;
  const int lane = tid & 63, wid = tid >> 6;
  const int quad = lane >> 4, lc = lane & 15;
  #pragma unroll
  for (int it = 0; it < 16; ++it) {
    int i = it * 256 + tid;
    int c = i >> 4, xs = (i & 15) * 4;
    float4 v = *reinterpret_cast<const float4*>(x + ((size_t)(b * NC + c)) * NP + y * NW + xs);
    As[xs + 0][c] = f2bf(v.x);
    As[xs + 1][c] = f2bf(v.y);
    As[xs + 2][c] = f2bf(v.z);
    As[xs + 3][c] = f2bf(v.w);
  }
  __syncthreads();
  const int wm = (wid & 1) * 32, wn = (wid >> 1) * 64;
  f32x4 acc[2][4] = {};
  #pragma unroll
  for (int ks = 0; ks < 8; ++ks) {
    const int k0 = ks * 32 + quad * 8;
    Frag a[2];
    bf16x8 bb[4];
    #pragma unroll
    for (int mt = 0; mt < 2; ++mt)
      a[mt].u4 = *reinterpret_cast<const uint4*>(&As[wm + mt * 16 + lc][k0]);
    #pragma unroll
    for (int nt = 0; nt < 4; ++nt) {
      int oc = n0 + wn + nt * 16 + lc;
      bb[nt] = load_bf8(wkv + (size_t)oc * NC + k0);
    }
    #pragma unroll
    for (int mt = 0; mt < 2; ++mt)
      #pragma unroll
      for (int nt = 0; nt < 4; ++nt)
        acc[mt][nt] = __builtin_amdgcn_mfma_f32_16x16x32_bf16(a[mt].b8, bb[nt], acc[mt][nt], 0, 0, 0);
  }
  #pragma unroll
  for (int mt = 0; mt < 2; ++mt) {
    #pragma unroll
    for (int r = 0; r < 4; ++r) {
      int pl = wm + mt * 16 + quad * 4 + r;
      #pragma unroll
      for (int nt = 0; nt < 4; ++nt) {
        int oc = n0 + wn + nt * 16 + lc;
        kvb[((size_t)(b * NP + y * NW + pl)) * NKV + oc] = f2bf(acc[mt][nt][r]);
      }
    }
  }
}

__global__ __launch_bounds__(256) void k_attn_v3(const float* __restrict__ x,
                                                 const float* __restrict__ wq,
                                                 const ushort* __restrict__ kvb,
                                                 const float* __restrict__ pbias,
                                                 float* __restrict__ out) {
  __shared__ __align__(16) ushort ksh[NPAD][40];
  __shared__ __align__(16) ushort vth[32][232];
  __shared__ __align__(16) ushort psh[4][16][232];
  __shared__ __align__(16) ushort qsh[4][16][32];
  __shared__ __align__(16) float osh[64][33];
  const int b = blockIdx.z, h = blockIdx.y, blk = blockIdx.x;
  const int by = blk >> 3, bx = blk & 7;
  const int tid = threadIdx.x, lane = tid & 63, w = tid >> 6;
  const int quad = lane >> 4, lc = lane & 15;

  for (int it = 0; it < 7; ++it) {
    int i = it * 256 + tid;
    int pos = i >> 3, seg = i & 7;
    Frag v;
    v.u4 = make_uint4(0u, 0u, 0u, 0u);
    if (pos < NPOS) {
      int wy = pos / WIN;
      int wx = pos - wy * WIN;
      int yq = by * 8 - 3 + wy, xx = bx * 8 - 3 + wx;
      if ((unsigned)yq < (unsigned)NH && (unsigned)xx < (unsigned)NW)
        v.u4 = *reinterpret_cast<const uint4*>(
            kvb + ((size_t)(b * NP + yq * NW + xx)) * NKV + h * 64 + seg * 8);
    }
    if (seg < 4) {
      *reinterpret_cast<uint4*>(&ksh[pos][seg * 8]) = v.u4;
    } else {
      int d0 = (seg - 4) * 8;
      #pragma unroll
      for (int j = 0; j < 8; ++j) vth[d0 + j][pos] = v.us[j];
    }
  }

  f32x4 qacc[2] = {};
  {
    const int q = w * 16 + lc;
    const size_t p = (size_t)(by * 8 + (q >> 3)) * NW + bx * 8 + (q & 7);
    #pragma unroll
    for (int ks = 0; ks < 8; ++ks) {
      const int k0 = ks * 32 + quad * 8;
      Frag ax;
      #pragma unroll
      for (int j = 0; j < 8; ++j)
        ax.us[j] = f2bf(x[((size_t)(b * NC + k0 + j)) * NP + p]);
      bf16x8 bw0 = load_bf8(wq + (size_t)(h * 32 + lc) * NC + k0);
      bf16x8 bw1 = load_bf8(wq + (size_t)(h * 32 + 16 + lc) * NC + k0);
      qacc[0] = __builtin_amdgcn_mfma_f32_16x16x32_bf16(ax.b8, bw0, qacc[0], 0, 0, 0);
      qacc[1] = __builtin_amdgcn_mfma_f32_16x16x32_bf16(ax.b8, bw1, qacc[1], 0, 0, 0);
    }
  }
  #pragma unroll
  for (int t = 0; t < 2; ++t)
    #pragma unroll
    for (int r = 0; r < 4; ++r)
      qsh[w][quad * 4 + r][t * 16 + lc] = f2bf(qacc[t][r]);
  Frag aq;
  aq.u4 = *reinterpret_cast<const uint4*>(&qsh[w][lc][quad * 8]);

  __syncthreads();

  f32x4 s[14];
  #pragma unroll
  for (int nt = 0; nt < 14; ++nt) {
    Frag bk;
    bk.u4 = *reinterpret_cast<const uint4*>(&ksh[nt * 16 + lc][quad * 8]);
    f32x4 z = {0.f, 0.f, 0.f, 0.f};
    s[nt] = __builtin_amdgcn_mfma_f32_16x16x32_bf16(aq.b8, bk.b8, z, 0, 0, 0);
  }

  const float scale = 0.17677669529663687f;
  const int qi = w * 16 + quad * 4;
  float lsum[4] = {0.f, 0.f, 0.f, 0.f};
  #pragma unroll
  for (int nt = 0; nt < 14; ++nt) {
    int col = nt * 16 + lc;
    #pragma unroll
    for (int r = 0; r < 4; ++r) {
      float p = 0.f;
      if (col < NPOS)
        p = __expf(s[nt][r] * scale + pbias[(size_t)(h * 64 + qi + r) * NPOS + col]);
      s[nt][r] = p;
      lsum[r] += p;
    }
  }
  #pragma unroll
  for (int m = 1; m < 16; m <<= 1) {
    #pragma unroll
    for (int r = 0; r < 4; ++r) lsum[r] += __shfl_xor(lsum[r], m);
  }
  #pragma unroll
  for (int nt = 0; nt < 14; ++nt) {
    #pragma unroll
    for (int r = 0; r < 4; ++r) psh[w][quad * 4 + r][nt * 16 + lc] = f2bf(s[nt][r]);
  }
  f32x4 o[2] = {};
  #pragma unroll
  for (int kt = 0; kt < 7; ++kt) {
    Frag ap;
    ap.u4 = *reinterpret_cast<const uint4*>(&psh[w][lc][kt * 32 + quad * 8]);
    #pragma unroll
    for (int t = 0; t < 2; ++t) {
      Frag bv;
      bv.u4 = *reinterpret_cast<const uint4*>(&vth[t * 16 + lc][kt * 32 + quad * 8]);
      o[t] = __builtin_amdgcn_mfma_f32_16x16x32_bf16(ap.b8, bv.b8, o[t], 0, 0, 0);
    }
  }
  #pragma unroll
  for (int t = 0; t < 2; ++t)
    #pragma unroll
    for (int r = 0; r < 4; ++r)
      osh[w * 16 + quad * 4 + r][t * 16 + lc] = o[t][r] / lsum[r];
  __syncthreads();
  {
    int d = tid >> 3, yy = tid & 7;
    float4 o0, o1;
    o0.x = osh[yy * 8 + 0][d]; o0.y = osh[yy * 8 + 1][d];
    o0.z = osh[yy * 8 + 2][d]; o0.w = osh[yy * 8 + 3][d];
    o1.x = osh[yy * 8 + 4][d]; o1.y = osh[yy * 8 + 5][d];
    o1.z = osh[yy * 8 + 6][d]; o1.w = osh[yy * 8 + 7][d];
    float* op = out + ((size_t)(b * NC + h * 32 + d) * NH + by * 8 + yy) * NW + bx * 8;
    *reinterpret_cast<float4*>(op) = o0;
    *reinterpret_cast<float4*>(op + 4) = o1;
  }
}

// ---------------------------------------------------------------------------
extern "C" void kernel_launch(void* const* d_in, const int* in_sizes, int n_in,
                              void* d_out, int out_size, void* d_ws, size_t ws_size,
                              hipStream_t stream) {
  const float* x   = (const float*)d_in[0];  // (16,256,64,64) f32
  const float* wq  = (const float*)d_in[1];  // (256,256) f32
  const float* wkv = (const float*)d_in[2];  // (512,256) f32
  const float* pb  = (const float*)d_in[3];  // (8,64,196) f32
  float* outp = (float*)d_out;               // (16,256,64,64) f32

  const size_t qkv_bytes = (size_t)NB * NP * NOC * sizeof(ushort);  // 96 MiB
  const size_t xt_bytes  = (size_t)NB * NP * NC * sizeof(ushort);   // 32 MiB

  if (ws_size >= qkv_bytes + xt_bytes) {
    // FULL: prep (wcast+pbias) + swizzled transpose + DMA-staged GEMM + attn
    ushort* qkv = (ushort*)d_ws;
    ushort* xt  = (ushort*)((char*)d_ws + qkv_bytes);
    k_prep<<<dim3(608), 256, 0, stream>>>(wq, wkv, pb);
    k_xt<<<dim3(NP / 64, NC / 64, NB), 256, 0, stream>>>(x, xt);
    k_proj2<<<dim3(NB * NP / 128, 3), 256, 0, stream>>>(xt, qkv);
    k_attn_f2<<<dim3(NB * HEADS * 64), 256, 0, stream>>>(qkv, outp);
  } else if (ws_size >= qkv_bytes) {
    ushort* qkv = (ushort*)d_ws;
    k_prep<<<dim3(608), 256, 0, stream>>>(wq, wkv, pb);
    k_proj_r4<<<dim3(NH, 3, NB), 256, 0, stream>>>(x, wq, wkv, qkv);
    k_attn_f2<<<dim3(NB * HEADS * 64), 256, 0, stream>>>(qkv, outp);
  } else {
    ushort* kvb = (ushort*)d_ws;               // 64 MiB
    k_kv<<<dim3(NH, NKV / 128, NB), 256, 0, stream>>>(x, wkv, kvb);
    k_attn_v3<<<dim3(64, HEADS, NB), 256, 0, stream>>>(x, wq, kvb, pb, outp);
  }
}

// Round 5
// 288.956 us; speedup vs baseline: 1.0492x; 1.0304x over previous
//
#include <hip/hip_runtime.h>
#include <hip/hip_bf16.h>
#include <stdint.h>

// Problem constants (B,C,H,W)=(16,256,64,64), HEADS=8, BS=8, HALO=3
#define HEADS 8
#define WIN 14
#define NPOS 196          // WIN*WIN
#define NPAD 224          // padded key count = 7*32
#define NB 16
#define NC 256
#define NH 64
#define NW 64
#define NP 4096           // NH*NW
#define NKV 512           // kv channels (fallback layout)
#define NOC 768           // q(256) + kv(512) channels

typedef __bf16 bf16_t;
typedef bf16_t bf16x8 __attribute__((ext_vector_type(8)));
typedef float f32x4 __attribute__((ext_vector_type(4)));

union Frag {
  uint4 u4;
  bf16x8 b8;
  ushort us[8];
};

__device__ __forceinline__ ushort f2bf(float f) {
  bf16_t h = (bf16_t)f;
  return __builtin_bit_cast(ushort, h);
}
__device__ __forceinline__ bf16x8 load_bf8(const float* __restrict__ p) {
  float4 a = *reinterpret_cast<const float4*>(p);
  float4 b = *reinterpret_cast<const float4*>(p + 4);
  bf16x8 r;
  r[0] = (bf16_t)a.x; r[1] = (bf16_t)a.y; r[2] = (bf16_t)a.z; r[3] = (bf16_t)a.w;
  r[4] = (bf16_t)b.x; r[5] = (bf16_t)b.y; r[6] = (bf16_t)b.z; r[7] = (bf16_t)b.w;
  return r;
}

// direct global->LDS DMA, 16B per lane
__device__ __forceinline__ void gload_lds16(const ushort* g, ushort* l) {
#if __has_builtin(__builtin_amdgcn_global_load_lds)
  __builtin_amdgcn_global_load_lds(
      (const __attribute__((address_space(1))) unsigned int*)(const void*)g,
      (__attribute__((address_space(3))) unsigned int*)(void*)l, 16, 0, 0);
#else
  *reinterpret_cast<uint4*>(l) = *reinterpret_cast<const uint4*>(g);
#endif
}

// bf16 weights, converted once per launch (same data every call)
__device__ ushort g_wb[NOC * NC];
// per-lane-layout bias for swapped-QK softmax:
// g_pb2[((h*4+w)*14+nt)*256 + lane*4 + r] = log2e * pb[h*64+w*16+lc][nt*16+quad*4+r]
// (lane = quad*16+lc), pad keys (>=196) = -1e5.
__device__ float g_pb2[HEADS * 4 * 14 * 256];

// ===========================================================================
// k_prep: wg<96 -> weight cast to g_wb; wg in [96,544) -> bias relayout g_pb2.
// ===========================================================================
__global__ __launch_bounds__(256) void k_prep(const float* __restrict__ wq,
                                              const float* __restrict__ wkv,
                                              const float* __restrict__ pb) {
  const int wg = blockIdx.x;
  const int tid = threadIdx.x;
  if (wg < 96) {
    int idx = (wg * 256 + tid) * 8;
    int oc = idx >> 8, c = idx & 255;
    const float* src = (oc < 256) ? (wq + (size_t)oc * NC + c)
                                  : (wkv + (size_t)(oc - 256) * NC + c);
    Frag v;
    v.b8 = load_bf8(src);
    *reinterpret_cast<uint4*>(g_wb + idx) = v.u4;
  } else {
    int idx2 = wg - 96;                   // ((h*4+w)*14+nt), 0..447
    int h = idx2 / 56;
    int rem = idx2 - h * 56;
    int w = rem / 14;
    int nt = rem - w * 14;
    int lane = tid >> 2, r = tid & 3;
    int quad = lane >> 4, lc = lane & 15;
    int q = w * 16 + lc;
    int key = nt * 16 + quad * 4 + r;
    float v = -100000.0f;
    if (key < NPOS)
      v = pb[((size_t)(h * 64 + q)) * NPOS + key] * 1.4426950408889634f;
    g_pb2[(size_t)idx2 * 256 + tid] = v;
  }
}

// ===========================================================================
// k_xt: x[b][c][p] f32 -> xt[b*NP+p][c] bf16, 16B-granule XOR-swizzled:
// granule g of row r stored at g ^ (r&7). Consumed only by k_proj2, which
// reads with the same XOR (both-sides swizzle so global_load_lds stays linear).
// ===========================================================================
__global__ __launch_bounds__(256) void k_xt(const float* __restrict__ x,
                                            ushort* __restrict__ xt) {
  __shared__ __align__(16) ushort ls[64][66];
  const int b = blockIdx.z, p0 = blockIdx.x * 64, c0 = blockIdx.y * 64;
  const int by8 = blockIdx.y * 8;
  const int tid = threadIdx.x;
  #pragma unroll
  for (int it = 0; it < 4; ++it) {
    int i = it * 256 + tid;
    int c = i >> 4, ps = (i & 15) * 4;
    float4 v = *reinterpret_cast<const float4*>(x + ((size_t)(b * NC + c0 + c)) * NP + p0 + ps);
    ls[ps + 0][c] = f2bf(v.x);
    ls[ps + 1][c] = f2bf(v.y);
    ls[ps + 2][c] = f2bf(v.z);
    ls[ps + 3][c] = f2bf(v.w);
  }
  __syncthreads();
  #pragma unroll
  for (int it = 0; it < 2; ++it) {
    int i = it * 256 + tid;
    int p = i >> 3, gl = i & 7;
    Frag o;
    #pragma unroll
    for (int j = 0; j < 8; ++j) o.us[j] = ls[p][gl * 8 + j];
    int gph = by8 + (gl ^ (p & 7));
    *reinterpret_cast<uint4*>(xt + ((size_t)(b * NP) + p0 + p) * NC + gph * 8) = o.u4;
  }
}

// ===========================================================================
// k_proj2: qkv[row][oc] = sum_c xt[row][c] * wb[oc][c]. M=65536 rows.
// 64KB linear LDS A-tile (whole K=256) filled via global_load_lds; A-reads
// undo the source XOR swizzle -> conflict-free ds_read_b128. One barrier pair.
// ===========================================================================
__global__ __launch_bounds__(256, 2) void k_proj2(const ushort* __restrict__ xt,
                                                  ushort* __restrict__ qkv) {
  __shared__ __align__(16) ushort As[128 * 256];   // 64 KB, linear
  const int row0 = blockIdx.x * 128;
  const int n0 = blockIdx.y * 256;
  const int tid = threadIdx.x, lane = tid & 63, wid = tid >> 6;
  const int quad = lane >> 4, lc = lane & 15;
  const ushort* gs = xt + (size_t)row0 * NC;
  #pragma unroll
  for (int it = 0; it < 16; ++it) {
    int f = it * 256 + tid;
    gload_lds16(gs + (size_t)f * 8, As + f * 8);
  }
  __syncthreads();
  const int wm = (wid & 1) * 64, wn = (wid >> 1) * 128;
  f32x4 acc[4][8] = {};
  #pragma unroll
  for (int ks = 0; ks < 8; ++ks) {
    const int k0 = ks * 32 + quad * 8;
    Frag a[4];
    #pragma unroll
    for (int mt = 0; mt < 4; ++mt) {
      int row = wm + mt * 16 + lc;                 // row&7 == lc&7
      int gk = (ks * 4 + quad) ^ (lc & 7);         // undo source swizzle
      a[mt].u4 = *reinterpret_cast<const uint4*>(&As[row * 256 + gk * 8]);
    }
    #pragma unroll
    for (int ng = 0; ng < 2; ++ng) {
      Frag bb[4];
      #pragma unroll
      for (int j = 0; j < 4; ++j) {
        int oc = n0 + wn + (ng * 4 + j) * 16 + lc;
        bb[j].u4 = *reinterpret_cast<const uint4*>(g_wb + (size_t)oc * NC + k0);
      }
      #pragma unroll
      for (int mt = 0; mt < 4; ++mt)
        #pragma unroll
        for (int j = 0; j < 4; ++j)
          acc[mt][ng * 4 + j] = __builtin_amdgcn_mfma_f32_16x16x32_bf16(
              a[mt].b8, bb[j].b8, acc[mt][ng * 4 + j], 0, 0, 0);
    }
  }
  __syncthreads();
  #pragma unroll
  for (int mt = 0; mt < 4; ++mt)
    #pragma unroll
    for (int nn = 0; nn < 8; ++nn) {
      int row = wm + mt * 16 + quad * 4;
      #pragma unroll
      for (int r = 0; r < 4; ++r) {
        int rr = row + r;
        int col = wn + nn * 16 + lc;
        As[rr * 256 + (((col >> 3) ^ (rr & 7)) * 8) + (col & 7)] = f2bf(acc[mt][nn][r]);
      }
    }
  __syncthreads();
  #pragma unroll
  for (int it = 0; it < 16; ++it) {
    int i = it * 256 + tid;
    int r = i >> 5, g = i & 31;
    uint4 u = *reinterpret_cast<const uint4*>(&As[r * 256 + ((g ^ (r & 7)) * 8)]);
    *reinterpret_cast<uint4*>(qkv + ((size_t)(row0 + r)) * NOC + n0 + g * 8) = u;
  }
}

// ===========================================================================
// k_attn_f2: 1D grid 8192, XCD-swizzled. 4 waves x 16 queries.
// SWAPPED QK^T: s = mfma(K,Q) -> lane holds P[q=lc][keys quad*4+r (+16nt)].
// Softmax fully lane-local (coalesced g_pb2 float4 bias; lsum scalar).
// PV A-frag built IN REGISTERS (no psh round-trip); V gathered as 2x b64
// per t with matching k-slot permutation. LDS 32 KB; osh overlays ksh.
// ===========================================================================
__global__ __launch_bounds__(256) void k_attn_f2(const ushort* __restrict__ qkv,
                                                 float* __restrict__ out) {
  __shared__ __align__(16) ushort ksh[NPAD][40];    // 17920 B; osh overlays
  __shared__ __align__(16) ushort vth[32][232];     // [d][key^swz], 14848 B
  float (*osh)[33] = reinterpret_cast<float(*)[33]>(&ksh[0][0]);  // 8448 B
  // bijective XCD swizzle: 8192 wg = 8 xcd x 1024; h fastest, then blk, then b
  const int orig = blockIdx.x;
  const int wgid = (orig & 7) * 1024 + (orig >> 3);
  const int h = wgid & 7;
  const int blk = (wgid >> 3) & 63;
  const int b = wgid >> 9;
  const int by = blk >> 3, bx = blk & 7;
  const int tid = threadIdx.x, lane = tid & 63, w = tid >> 6;
  const int quad = lane >> 4, lc = lane & 15;

  // q fragment straight from qkv (lane lc -> q=w*16+lc, k=quad*8+j)
  Frag aq;
  {
    int q = w * 16 + lc;
    int py = by * 8 + (q >> 3), px = bx * 8 + (q & 7);
    aq.u4 = *reinterpret_cast<const uint4*>(
        qkv + ((size_t)(b * NP + py * NW + px)) * NOC + h * 32 + quad * 8);
  }

  // stage KV window: 224 pos x 8 segs; segs 0..3 -> k, 4..7 -> v^T (swizzled)
  #pragma unroll
  for (int it = 0; it < 7; ++it) {
    int i = it * 256 + tid;
    int pos = i >> 3, seg = i & 7;
    Frag v;
    v.u4 = make_uint4(0u, 0u, 0u, 0u);
    if (pos < NPOS) {
      int wy = pos / WIN;
      int wx = pos - wy * WIN;
      int yq = by * 8 - 3 + wy, xx = bx * 8 - 3 + wx;
      if ((unsigned)yq < (unsigned)NH && (unsigned)xx < (unsigned)NW)
        v.u4 = *reinterpret_cast<const uint4*>(
            qkv + ((size_t)(b * NP + yq * NW + xx)) * NOC + 256 + h * 64 + seg * 8);
    }
    if (seg < 4) {
      *reinterpret_cast<uint4*>(&ksh[pos][seg * 8]) = v.u4;
    } else {
      int d0 = (seg - 4) * 8;
      int cp = pos ^ ((seg - 4) << 3);   // XOR swizzle on key index
      #pragma unroll
      for (int j = 0; j < 8; ++j) vth[d0 + j][cp] = v.us[j];
    }
  }
  __syncthreads();

  // S^T = K q^T : swapped operands -> lane holds P[q=lc][key=nt*16+quad*4+r]
  f32x4 s[14];
  __builtin_amdgcn_s_setprio(1);
  #pragma unroll
  for (int nt = 0; nt < 14; ++nt) {
    Frag bk;
    bk.u4 = *reinterpret_cast<const uint4*>(&ksh[nt * 16 + lc][quad * 8]);
    f32x4 z = {0.f, 0.f, 0.f, 0.f};
    s[nt] = __builtin_amdgcn_mfma_f32_16x16x32_bf16(bk.b8, aq.b8, z, 0, 0, 0);
  }
  __builtin_amdgcn_s_setprio(0);

  // softmax: p = exp2(s*ck + bias_pre); bias fully coalesced from g_pb2.
  const float ck = 0.17677669529663687f * 1.4426950408889634f;
  const float* __restrict__ pbw = g_pb2 + (size_t)((h * 4 + w) * 14) * 256;
  float lsum = 0.f;
  #pragma unroll
  for (int nt = 0; nt < 14; ++nt) {
    float4 bv4 = *reinterpret_cast<const float4*>(pbw + nt * 256 + lane * 4);
    #pragma unroll
    for (int r = 0; r < 4; ++r) {
      float p = exp2f(s[nt][r] * ck + (&bv4.x)[r]);
      s[nt][r] = p;
      lsum += p;
    }
  }

  // O = P V : 7 slabs of 32 keys. A-frag in registers, k-slot order
  // key(quad,j) = kt*32 + (j>>2)*16 + quad*4 + (j&3); V gathered to match.
  f32x4 o[2] = {};
  #pragma unroll
  for (int kt = 0; kt < 7; ++kt) {
    Frag pa;
    #pragma unroll
    for (int j = 0; j < 8; ++j)
      pa.us[j] = f2bf(s[2 * kt + (j >> 2)][j & 3]);
    #pragma unroll
    for (int t = 0; t < 2; ++t) {
      int d = t * 16 + lc;
      int xr = ((d >> 3) & 3) << 3;
      int c0 = (kt * 32 + quad * 4) ^ xr;
      int c1 = (kt * 32 + 16 + quad * 4) ^ xr;
      Frag bv;
      *reinterpret_cast<uint2*>(&bv.us[0]) = *reinterpret_cast<const uint2*>(&vth[d][c0]);
      *reinterpret_cast<uint2*>(&bv.us[4]) = *reinterpret_cast<const uint2*>(&vth[d][c1]);
      o[t] = __builtin_amdgcn_mfma_f32_16x16x32_bf16(pa.b8, bv.b8, o[t], 0, 0, 0);
    }
  }

  // row-sum finish: reduce over quads (each lane then holds S[q=lc]),
  // broadcast reciprocal to the lanes that own row q=quad*4+r in C-layout.
  lsum += __shfl_xor(lsum, 16);
  lsum += __shfl_xor(lsum, 32);
  float rl = 1.0f / lsum;
  float rinv[4];
  #pragma unroll
  for (int r = 0; r < 4; ++r)
    rinv[r] = __shfl(rl, (lane & 48) + quad * 4 + r);

  __syncthreads();   // all waves done reading ksh before osh overlay write
  #pragma unroll
  for (int t = 0; t < 2; ++t)
    #pragma unroll
    for (int r = 0; r < 4; ++r)
      osh[w * 16 + quad * 4 + r][t * 16 + lc] = o[t][r] * rinv[r];
  __syncthreads();

  // write: out[b][h*32+d][by*8+yy][bx*8..+8], f32, two float4 per lane
  {
    int d = tid >> 3, yy = tid & 7;
    float4 o0, o1;
    o0.x = osh[yy * 8 + 0][d]; o0.y = osh[yy * 8 + 1][d];
    o0.z = osh[yy * 8 + 2][d]; o0.w = osh[yy * 8 + 3][d];
    o1.x = osh[yy * 8 + 4][d]; o1.y = osh[yy * 8 + 5][d];
    o1.z = osh[yy * 8 + 6][d]; o1.w = osh[yy * 8 + 7][d];
    float* op = out + ((size_t)(b * NC + h * 32 + d) * NH + by * 8 + yy) * NW + bx * 8;
    *reinterpret_cast<float4*>(op) = o0;
    *reinterpret_cast<float4*>(op + 4) = o1;
  }
}

// ===========================================================================
// MID FALLBACK (96 MiB <= ws < 128 MiB): R4 k_proj (proven) + k_attn_f2
// ===========================================================================
__global__ __launch_bounds__(256) void k_proj_r4(const float* __restrict__ x,
                                                 const float* __restrict__ wq,
                                                 const float* __restrict__ wkv,
                                                 ushort* __restrict__ qkv) {
  __shared__ __align__(16) ushort As[64][264];
  const int b = blockIdx.z, y = blockIdx.x;
  const int n0 = blockIdx.y * 256;
  const int tid = threadIdx.x, lane = tid & 63, wid = tid >> 6;
  const int quad = lane >> 4, lc = lane & 15;
  #pragma unroll
  for (int it = 0; it < 16; ++it) {
    int i = it * 256 + tid;
    int c = i >> 4, xs = (i & 15) * 4;
    float4 v = *reinterpret_cast<const float4*>(x + ((size_t)(b * NC + c)) * NP + y * NW + xs);
    #pragma unroll
    for (int j = 0; j < 4; ++j) {
      int row = xs + j;
      float f = (j == 0) ? v.x : (j == 1) ? v.y : (j == 2) ? v.z : v.w;
      As[row][c ^ ((((row >> 2) & 3)) << 3)] = f2bf(f);
    }
  }
  __syncthreads();
  const int wm = (wid & 1) * 32, wn = (wid >> 1) * 128;
  const int swz = ((lc >> 2) & 3) << 3;
  f32x4 acc[2][8] = {};
  #pragma unroll
  for (int ks = 0; ks < 8; ++ks) {
    const int k0 = ks * 32 + quad * 8;
    Frag a0, a1;
    a0.u4 = *reinterpret_cast<const uint4*>(&As[wm + lc][k0 ^ swz]);
    a1.u4 = *reinterpret_cast<const uint4*>(&As[wm + 16 + lc][k0 ^ swz]);
    #pragma unroll
    for (int nh = 0; nh < 2; ++nh) {
      bf16x8 bb[4];
      #pragma unroll
      for (int nt = 0; nt < 4; ++nt) {
        int oc = n0 + wn + nh * 64 + nt * 16 + lc;
        const float* wp = (oc < 256) ? (wq + (size_t)oc * NC) : (wkv + (size_t)(oc - 256) * NC);
        bb[nt] = load_bf8(wp + k0);
      }
      #pragma unroll
      for (int nt = 0; nt < 4; ++nt) {
        acc[0][nh * 4 + nt] = __builtin_amdgcn_mfma_f32_16x16x32_bf16(a0.b8, bb[nt], acc[0][nh * 4 + nt], 0, 0, 0);
        acc[1][nh * 4 + nt] = __builtin_amdgcn_mfma_f32_16x16x32_bf16(a1.b8, bb[nt], acc[1][nh * 4 + nt], 0, 0, 0);
      }
    }
  }
  __syncthreads();
  #pragma unroll
  for (int mt = 0; mt < 2; ++mt)
    #pragma unroll
    for (int nn = 0; nn < 8; ++nn)
      #pragma unroll
      for (int r = 0; r < 4; ++r)
        As[wm + mt * 16 + quad * 4 + r][wn + nn * 16 + lc] = f2bf(acc[mt][nn][r]);
  __syncthreads();
  #pragma unroll
  for (int v8 = 0; v8 < 8; ++v8) {
    int flat = v8 * 256 + tid;
    int p = flat >> 5, seg = flat & 31;
    uint4 u = *reinterpret_cast<const uint4*>(&As[p][seg * 8]);
    *reinterpret_cast<uint4*>(qkv + ((size_t)(b * NP) + y * NW + p) * NOC + n0 + seg * 8) = u;
  }
}

// ===========================================================================
// LOW FALLBACK (ws < 96 MiB): Round-3 kernels, proven correct
// ===========================================================================
__global__ __launch_bounds__(256) void k_kv(const float* __restrict__ x,
                                            const float* __restrict__ wkv,
                                            ushort* __restrict__ kvb) {
  __shared__ __align__(16) ushort As[64][264];
  const int b = blockIdx.z;
  const int y = blockIdx.x;
  const int n0 = blockIdx.y * 128;
  const int tid = threadIdx.x;
  const int lane = tid & 63, wid = tid >> 6;
  const int quad = lane >> 4, lc = lane & 15;
  #pragma unroll
  for (int it = 0; it < 16; ++it) {
    int i = it * 256 + tid;
    int c = i >> 4, xs = (i & 15) * 4;
    float4 v = *reinterpret_cast<const float4*>(x + ((size_t)(b * NC + c)) * NP + y * NW + xs);
    As[xs + 0][c] = f2bf(v.x);
    As[xs + 1][c] = f2bf(v.y);
    As[xs + 2][c] = f2bf(v.z);
    As[xs + 3][c] = f2bf(v.w);
  }
  __syncthreads();
  const int wm = (wid & 1) * 32, wn = (wid >> 1) * 64;
  f32x4 acc[2][4] = {};
  #pragma unroll
  for (int ks = 0; ks < 8; ++ks) {
    const int k0 = ks * 32 + quad * 8;
    Frag a[2];
    bf16x8 bb[4];
    #pragma unroll
    for (int mt = 0; mt < 2; ++mt)
      a[mt].u4 = *reinterpret_cast<const uint4*>(&As[wm + mt * 16 + lc][k0]);
    #pragma unroll
    for (int nt = 0; nt < 4; ++nt) {
      int oc = n0 + wn + nt * 16 + lc;
      bb[nt] = load_bf8(wkv + (size_t)oc * NC + k0);
    }
    #pragma unroll
    for (int mt = 0; mt < 2; ++mt)
      #pragma unroll
      for (int nt = 0; nt < 4; ++nt)
        acc[mt][nt] = __builtin_amdgcn_mfma_f32_16x16x32_bf16(a[mt].b8, bb[nt], acc[mt][nt], 0, 0, 0);
  }
  #pragma unroll
  for (int mt = 0; mt < 2; ++mt) {
    #pragma unroll
    for (int r = 0; r < 4; ++r) {
      int pl = wm + mt * 16 + quad * 4 + r;
      #pragma unroll
      for (int nt = 0; nt < 4; ++nt) {
        int oc = n0 + wn + nt * 16 + lc;
        kvb[((size_t)(b * NP + y * NW + pl)) * NKV + oc] = f2bf(acc[mt][nt][r]);
      }
    }
  }
}

__global__ __launch_bounds__(256) void k_attn_v3(const float* __restrict__ x,
                                                 const float* __restrict__ wq,
                                                 const ushort* __restrict__ kvb,
                                                 const float* __restrict__ pbias,
                                                 float* __restrict__ out) {
  __shared__ __align__(16) ushort ksh[NPAD][40];
  __shared__ __align__(16) ushort vth[32][232];
  __shared__ __align__(16) ushort psh[4][16][232];
  __shared__ __align__(16) ushort qsh[4][16][32];
  __shared__ __align__(16) float osh[64][33];
  const int b = blockIdx.z, h = blockIdx.y, blk = blockIdx.x;
  const int by = blk >> 3, bx = blk & 7;
  const int tid = threadIdx.x, lane = tid & 63, w = tid >> 6;
  const int quad = lane >> 4, lc = lane & 15;

  for (int it = 0; it < 7; ++it) {
    int i = it * 256 + tid;
    int pos = i >> 3, seg = i & 7;
    Frag v;
    v.u4 = make_uint4(0u, 0u, 0u, 0u);
    if (pos < NPOS) {
      int wy = pos / WIN;
      int wx = pos - wy * WIN;
      int yq = by * 8 - 3 + wy, xx = bx * 8 - 3 + wx;
      if ((unsigned)yq < (unsigned)NH && (unsigned)xx < (unsigned)NW)
        v.u4 = *reinterpret_cast<const uint4*>(
            kvb + ((size_t)(b * NP + yq * NW + xx)) * NKV + h * 64 + seg * 8);
    }
    if (seg < 4) {
      *reinterpret_cast<uint4*>(&ksh[pos][seg * 8]) = v.u4;
    } else {
      int d0 = (seg - 4) * 8;
      #pragma unroll
      for (int j = 0; j < 8; ++j) vth[d0 + j][pos] = v.us[j];
    }
  }

  f32x4 qacc[2] = {};
  {
    const int q = w * 16 + lc;
    const size_t p = (size_t)(by * 8 + (q >> 3)) * NW + bx * 8 + (q & 7);
    #pragma unroll
    for (int ks = 0; ks < 8; ++ks) {
      const int k0 = ks * 32 + quad * 8;
      Frag ax;
      #pragma unroll
      for (int j = 0; j < 8; ++j)
        ax.us[j] = f2bf(x[((size_t)(b * NC + k0 + j)) * NP + p]);
      bf16x8 bw0 = load_bf8(wq + (size_t)(h * 32 + lc) * NC + k0);
      bf16x8 bw1 = load_bf8(wq + (size_t)(h * 32 + 16 + lc) * NC + k0);
      qacc[0] = __builtin_amdgcn_mfma_f32_16x16x32_bf16(ax.b8, bw0, qacc[0], 0, 0, 0);
      qacc[1] = __builtin_amdgcn_mfma_f32_16x16x32_bf16(ax.b8, bw1, qacc[1], 0, 0, 0);
    }
  }
  #pragma unroll
  for (int t = 0; t < 2; ++t)
    #pragma unroll
    for (int r = 0; r < 4; ++r)
      qsh[w][quad * 4 + r][t * 16 + lc] = f2bf(qacc[t][r]);
  Frag aq;
  aq.u4 = *reinterpret_cast<const uint4*>(&qsh[w][lc][quad * 8]);

  __syncthreads();

  f32x4 s[14];
  #pragma unroll
  for (int nt = 0; nt < 14; ++nt) {
    Frag bk;
    bk.u4 = *reinterpret_cast<const uint4*>(&ksh[nt * 16 + lc][quad * 8]);
    f32x4 z = {0.f, 0.f, 0.f, 0.f};
    s[nt] = __builtin_amdgcn_mfma_f32_16x16x32_bf16(aq.b8, bk.b8, z, 0, 0, 0);
  }

  const float scale = 0.17677669529663687f;
  const int qi = w * 16 + quad * 4;
  float lsum[4] = {0.f, 0.f, 0.f, 0.f};
  #pragma unroll
  for (int nt = 0; nt < 14; ++nt) {
    int col = nt * 16 + lc;
    #pragma unroll
    for (int r = 0; r < 4; ++r) {
      float p = 0.f;
      if (col < NPOS)
        p = __expf(s[nt][r] * scale + pbias[(size_t)(h * 64 + qi + r) * NPOS + col]);
      s[nt][r] = p;
      lsum[r] += p;
    }
  }
  #pragma unroll
  for (int m = 1; m < 16; m <<= 1) {
    #pragma unroll
    for (int r = 0; r < 4; ++r) lsum[r] += __shfl_xor(lsum[r], m);
  }
  #pragma unroll
  for (int nt = 0; nt < 14; ++nt) {
    #pragma unroll
    for (int r = 0; r < 4; ++r) psh[w][quad * 4 + r][nt * 16 + lc] = f2bf(s[nt][r]);
  }
  f32x4 o[2] = {};
  #pragma unroll
  for (int kt = 0; kt < 7; ++kt) {
    Frag ap;
    ap.u4 = *reinterpret_cast<const uint4*>(&psh[w][lc][kt * 32 + quad * 8]);
    #pragma unroll
    for (int t = 0; t < 2; ++t) {
      Frag bv;
      bv.u4 = *reinterpret_cast<const uint4*>(&vth[t * 16 + lc][kt * 32 + quad * 8]);
      o[t] = __builtin_amdgcn_mfma_f32_16x16x32_bf16(ap.b8, bv.b8, o[t], 0, 0, 0);
    }
  }
  #pragma unroll
  for (int t = 0; t < 2; ++t)
    #pragma unroll
    for (int r = 0; r < 4; ++r)
      osh[w * 16 + quad * 4 + r][t * 16 + lc] = o[t][r] / lsum[r];
  __syncthreads();
  {
    int d = tid >> 3, yy = tid & 7;
    float4 o0, o1;
    o0.x = osh[yy * 8 + 0][d]; o0.y = osh[yy * 8 + 1][d];
    o0.z = osh[yy * 8 + 2][d]; o0.w = osh[yy * 8 + 3][d];
    o1.x = osh[yy * 8 + 4][d]; o1.y = osh[yy * 8 + 5][d];
    o1.z = osh[yy * 8 + 6][d]; o1.w = osh[yy * 8 + 7][d];
    float* op = out + ((size_t)(b * NC + h * 32 + d) * NH + by * 8 + yy) * NW + bx * 8;
    *reinterpret_cast<float4*>(op) = o0;
    *reinterpret_cast<float4*>(op + 4) = o1;
  }
}

// ---------------------------------------------------------------------------
extern "C" void kernel_launch(void* const* d_in, const int* in_sizes, int n_in,
                              void* d_out, int out_size, void* d_ws, size_t ws_size,
                              hipStream_t stream) {
  const float* x   = (const float*)d_in[0];  // (16,256,64,64) f32
  const float* wq  = (const float*)d_in[1];  // (256,256) f32
  const float* wkv = (const float*)d_in[2];  // (512,256) f32
  const float* pb  = (const float*)d_in[3];  // (8,64,196) f32
  float* outp = (float*)d_out;               // (16,256,64,64) f32

  const size_t qkv_bytes = (size_t)NB * NP * NOC * sizeof(ushort);  // 96 MiB
  const size_t xt_bytes  = (size_t)NB * NP * NC * sizeof(ushort);   // 32 MiB

  if (ws_size >= qkv_bytes + xt_bytes) {
    // FULL: prep (wcast+bias relayout) + swizzled transpose + GEMM + attn
    ushort* qkv = (ushort*)d_ws;
    ushort* xt  = (ushort*)((char*)d_ws + qkv_bytes);
    k_prep<<<dim3(544), 256, 0, stream>>>(wq, wkv, pb);
    k_xt<<<dim3(NP / 64, NC / 64, NB), 256, 0, stream>>>(x, xt);
    k_proj2<<<dim3(NB * NP / 128, 3), 256, 0, stream>>>(xt, qkv);
    k_attn_f2<<<dim3(NB * HEADS * 64), 256, 0, stream>>>(qkv, outp);
  } else if (ws_size >= qkv_bytes) {
    ushort* qkv = (ushort*)d_ws;
    k_prep<<<dim3(544), 256, 0, stream>>>(wq, wkv, pb);
    k_proj_r4<<<dim3(NH, 3, NB), 256, 0, stream>>>(x, wq, wkv, qkv);
    k_attn_f2<<<dim3(NB * HEADS * 64), 256, 0, stream>>>(qkv, outp);
  } else {
    ushort* kvb = (ushort*)d_ws;               // 64 MiB
    k_kv<<<dim3(NH, NKV / 128, NB), 256, 0, stream>>>(x, wkv, kvb);
    k_attn_v3<<<dim3(64, HEADS, NB), 256, 0, stream>>>(x, wq, kvb, pb, outp);
  }
}